// Round 2
// baseline (2990.283 us; speedup 1.0000x reference)
//
#include <hip/hip_runtime.h>
#include <stdint.h>
#include <string.h>

#define B_    1024
#define TX_   512
#define TY_   32
#define NA_   64
#define NS_   128
#define VIN_  64
#define VOUT_ 32

typedef short v8s __attribute__((ext_vector_type(8)));   // 8 bf16 (4 VGPRs)
typedef float v4f __attribute__((ext_vector_type(4)));   // 4 fp32 acc
typedef _Float16 h2 __attribute__((ext_vector_type(2))); // packed f16 pair

__device__ __forceinline__ unsigned short f2bf(float f) {
  union { float f; uint32_t u; } v; v.f = f;
  return (unsigned short)((v.u + 0x7fffu + ((v.u >> 16) & 1u)) >> 16);  // RNE
}
__device__ __forceinline__ float bflo(uint32_t p) { union { uint32_t u; float f; } v; v.u = p << 16; return v.f; }
__device__ __forceinline__ float bfhi(uint32_t p) { union { uint32_t u; float f; } v; v.u = p & 0xffff0000u; return v.f; }
__device__ __forceinline__ float sigm(float x)   { return 1.0f / (1.0f + __expf(-x)); }
__device__ __forceinline__ float tanh_f(float x) { return 1.0f - 2.0f / (__expf(2.0f * x) + 1.0f); }

__device__ __forceinline__ uint32_t packf16(float a, float b) {
  union { h2 h; uint32_t u; } v; v.h[0] = (_Float16)a; v.h[1] = (_Float16)b; return v.u;
}
__device__ __forceinline__ float dot2(uint32_t w, uint32_t x, float acc) {
  union { uint32_t u; h2 h; } a, b; a.u = w; b.u = x;
#if __has_builtin(__builtin_amdgcn_fdot2)
  return __builtin_amdgcn_fdot2(a.h, b.h, acc, false);
#else
  return acc + (float)a.h[0] * (float)b.h[0] + (float)a.h[1] * (float)b.h[1];
#endif
}

// ---------------- prep: Wcat = [Wih_p | Whh_p] -> f16, swizzled [k/8][j][8] for coalesced streaming
__global__ __launch_bounds__(256) void k_prep(const float* __restrict__ Wih_p,
                                              const float* __restrict__ Whh_p,
                                              unsigned short* __restrict__ Wsw) {
  int i = blockIdx.x * 256 + threadIdx.x;   // < 512*256
  int j = i >> 8, k = i & 255;
  float w = (k < 128) ? Wih_p[j * 128 + k] : Whh_p[j * 128 + (k - 128)];
  union { _Float16 h; unsigned short s; } cv; cv.h = (_Float16)w;
  Wsw[(((k >> 3) * 512 + j) << 3) + (k & 7)] = cv.s;
}

// ---------------- encoder: unchanged from R1 (passed; revisit next round)
__global__ __launch_bounds__(256) void k_enc(
    const float* __restrict__ X,
    const float* __restrict__ Wih_f, const float* __restrict__ Whh_f,
    const float* __restrict__ bih_f, const float* __restrict__ bhh_f,
    const float* __restrict__ Wih_b, const float* __restrict__ Whh_b,
    const float* __restrict__ bih_b, const float* __restrict__ bhh_b,
    unsigned short* __restrict__ pre16)
{
  const int tid = threadIdx.x, lane = tid & 63, wv = tid >> 6;
  const int dir = blockIdx.x & 1, b0 = (blockIdx.x >> 1) * 16;
  const int n = lane & 15, q = lane >> 4, hs = wv * 16;
  const float* Wih = dir ? Wih_b : Wih_f;
  const float* Whh = dir ? Whh_b : Whh_f;
  const float* bih = dir ? bih_b : bih_f;
  const float* bhh = dir ? bhh_b : bhh_f;

  __shared__ __align__(16) unsigned short hl[16 * 72];  // h bf16 [m][k], 144B row stride

  v8s wx[4][2], wh[4][2];
  float bias[4];
#pragma unroll
  for (int g = 0; g < 4; ++g) {
    int row = g * 64 + hs + n;
    bias[g] = bih[row] + bhh[row];
#pragma unroll
    for (int kt = 0; kt < 2; ++kt) {
      const float* pi = Wih + row * 64 + kt * 32 + q * 8;
      const float* ph = Whh + row * 64 + kt * 32 + q * 8;
      v8s a, bb;
#pragma unroll
      for (int j = 0; j < 8; ++j) { a[j] = (short)f2bf(pi[j]); bb[j] = (short)f2bf(ph[j]); }
      wx[g][kt] = a; wh[g][kt] = bb;
    }
  }
  for (int i = tid; i < 16 * 36; i += 256) ((uint32_t*)hl)[i] = 0u;

  float c[4] = {0.f, 0.f, 0.f, 0.f};
  const float* xrow = X + (size_t)(b0 + n) * (TX_ * VIN_) + q * 8;
  int t0 = dir ? (TX_ - 1) : 0;
  float4 pf0 = *(const float4*)(xrow + t0 * VIN_ + 0);
  float4 pf1 = *(const float4*)(xrow + t0 * VIN_ + 4);
  float4 pf2 = *(const float4*)(xrow + t0 * VIN_ + 32);
  float4 pf3 = *(const float4*)(xrow + t0 * VIN_ + 36);
  __syncthreads();

  for (int t = 0; t < TX_; ++t) {
    v8s xa0, xa1;
    xa0[0]=(short)f2bf(pf0.x); xa0[1]=(short)f2bf(pf0.y); xa0[2]=(short)f2bf(pf0.z); xa0[3]=(short)f2bf(pf0.w);
    xa0[4]=(short)f2bf(pf1.x); xa0[5]=(short)f2bf(pf1.y); xa0[6]=(short)f2bf(pf1.z); xa0[7]=(short)f2bf(pf1.w);
    xa1[0]=(short)f2bf(pf2.x); xa1[1]=(short)f2bf(pf2.y); xa1[2]=(short)f2bf(pf2.z); xa1[3]=(short)f2bf(pf2.w);
    xa1[4]=(short)f2bf(pf3.x); xa1[5]=(short)f2bf(pf3.y); xa1[6]=(short)f2bf(pf3.z); xa1[7]=(short)f2bf(pf3.w);
    int tn = (t + 1 < TX_) ? t + 1 : t;
    int ti = dir ? (TX_ - 1 - tn) : tn;
    pf0 = *(const float4*)(xrow + ti * VIN_ + 0);
    pf1 = *(const float4*)(xrow + ti * VIN_ + 4);
    pf2 = *(const float4*)(xrow + ti * VIN_ + 32);
    pf3 = *(const float4*)(xrow + ti * VIN_ + 36);

    v8s ha0 = *(const v8s*)((const char*)hl + (lane & 15) * 144 + q * 16);
    v8s ha1 = *(const v8s*)((const char*)hl + (lane & 15) * 144 + 64 + q * 16);
    v4f acc[4];
#pragma unroll
    for (int g = 0; g < 4; ++g) {
      v4f a = {bias[g], bias[g], bias[g], bias[g]};
      a = __builtin_amdgcn_mfma_f32_16x16x32_bf16(xa0, wx[g][0], a, 0, 0, 0);
      a = __builtin_amdgcn_mfma_f32_16x16x32_bf16(xa1, wx[g][1], a, 0, 0, 0);
      a = __builtin_amdgcn_mfma_f32_16x16x32_bf16(ha0, wh[g][0], a, 0, 0, 0);
      a = __builtin_amdgcn_mfma_f32_16x16x32_bf16(ha1, wh[g][1], a, 0, 0, 0);
      acc[g] = a;
    }
    __syncthreads();
    int t_out = dir ? (TX_ - 1 - t) : t;
#pragma unroll
    for (int r = 0; r < 4; ++r) {
      float cc = sigm(acc[1][r]) * c[r] + sigm(acc[0][r]) * tanh_f(acc[2][r]);
      c[r] = cc;
      float h = sigm(acc[3][r]) * tanh_f(cc);
      int m = q * 4 + r;
      unsigned short hb = f2bf(h);
      *((unsigned short*)((char*)hl + m * 144) + hs + n) = hb;
      pre16[((size_t)(b0 + m) * TX_ + t_out) * NS_ + dir * 64 + hs + n] = hb;
    }
    __syncthreads();
  }
}

// ---------------- decoder v2: 512 blocks x 512 thr, 2 batches/block, pre_out streamed from L2/L3
__global__ __launch_bounds__(512, 4) void k_dec(
    const unsigned short* __restrict__ pre16,
    const unsigned short* __restrict__ Wsw,   // f16 [k/8][j][8]
    const float* __restrict__ W1, const float* __restrict__ b1,
    const float* __restrict__ W2, const float* __restrict__ b2,
    const float* __restrict__ W3, const float* __restrict__ b3,
    const float* __restrict__ bih_p, const float* __restrict__ bhh_p,
    float* __restrict__ Lg)
{
  __shared__ __align__(16) unsigned short P[2][TX_ * 10];  // 20.5 KB, attn precomp bf16
  __shared__ float ea[2][TX_];                             // 4 KB  alphas
  __shared__ __align__(16) float red[1024];                // 4 KB  ctx partials [2][4][128] / logits [2][256]
  __shared__ float zbuf[2][512];                           // 4 KB
  __shared__ float sl[2][NS_];                             // 1 KB  s state
  __shared__ __align__(16) uint32_t xpk[2][NS_];           // 1 KB  f16x2 packed [ctx | s]
  __shared__ float qv[2][16];
  __shared__ float rr[2][16];                              // [b][0..7]=max, [b][8..15]=sum
  __shared__ float w1p[1280];                              // 5 KB  W1[:,128:] (prologue)

  const int tid = threadIdx.x, lane = tid & 63, wv = tid >> 6;
  const int b0 = blockIdx.x * 2;

  if (tid < 256) { int bb = tid >> 7, i = tid & 127; sl[bb][i] = 0.f; xpk[bb][i] = 0u; }
  for (int i = tid; i < 1280; i += 512) w1p[i] = W1[(i >> 7) * 256 + 128 + (i & 127)];
  __syncthreads();
  {  // P[b][t][g] = pre_out[b][t] @ W1[:,128:].T + b1   (thread = t, both batches)
    int t = tid;
#pragma unroll
    for (int bb = 0; bb < 2; ++bb) {
      const uint32_t* src = (const uint32_t*)(pre16 + ((size_t)(b0 + bb) * TX_ + t) * NS_);
      float a[10];
#pragma unroll
      for (int g = 0; g < 10; ++g) a[g] = b1[g];
      for (int k2 = 0; k2 < 64; ++k2) {
        uint32_t pr = src[k2];
        float lo = bflo(pr), hi = bfhi(pr);
#pragma unroll
        for (int g = 0; g < 10; ++g) a[g] += lo * w1p[g * 128 + 2 * k2] + hi * w1p[g * 128 + 2 * k2 + 1];
      }
#pragma unroll
      for (int g = 0; g < 10; ++g) P[bb][t * 10 + g] = f2bf(a[g]);
    }
  }
  float creg = 0.f;                          // c state for (tid>>7, tid&127) if tid<256
  float bpj = bih_p[tid] + bhh_p[tid];       // gate bias for row j=tid
  __syncthreads();

  for (int ty = 0; ty < TY_; ++ty) {
    // ---- q[b] = W1[:, :128] @ s[b]   (wave 0 -> batch 0, wave 1 -> batch 1)
    if (wv < 2) {
      int bb = wv;
      float s0 = sl[bb][lane], s1 = sl[bb][64 + lane];
      float p10[10];
#pragma unroll
      for (int g = 0; g < 10; ++g) p10[g] = s0 * W1[g * 256 + lane] + s1 * W1[g * 256 + 64 + lane];
#pragma unroll
      for (int off = 1; off < 64; off <<= 1) {
#pragma unroll
        for (int g = 0; g < 10; ++g) p10[g] += __shfl_xor(p10[g], off);
      }
      if (lane < 10) qv[bb][lane] = p10[lane];
    }
    __syncthreads();
    // ---- e_t + softmax over t, both batches (thread = t)
    {
      int t = tid;
      const uint32_t* Pt0 = (const uint32_t*)(const void*)&P[0][0] + t * 5;
      const uint32_t* Pt1 = (const uint32_t*)(const void*)&P[1][0] + t * 5;
      float a0 = b2[0], a1 = b2[0];
#pragma unroll
      for (int i = 0; i < 5; ++i) {
        uint32_t p0 = Pt0[i], p1 = Pt1[i];
        float w2a = W2[2 * i], w2b = W2[2 * i + 1];
        a0 += w2a * tanh_f(bflo(p0) + qv[0][2 * i]) + w2b * tanh_f(bfhi(p0) + qv[0][2 * i + 1]);
        a1 += w2a * tanh_f(bflo(p1) + qv[1][2 * i]) + w2b * tanh_f(bfhi(p1) + qv[1][2 * i + 1]);
      }
      float e0 = fmaxf(a0, 0.f), e1 = fmaxf(a1, 0.f);
      float m0 = e0, m1 = e1;
#pragma unroll
      for (int off = 1; off < 64; off <<= 1) { m0 = fmaxf(m0, __shfl_xor(m0, off)); m1 = fmaxf(m1, __shfl_xor(m1, off)); }
      if (lane == 0) { rr[0][wv] = m0; rr[1][wv] = m1; }
      __syncthreads();
      float mx0 = rr[0][0], mx1 = rr[1][0];
#pragma unroll
      for (int w = 1; w < 8; ++w) { mx0 = fmaxf(mx0, rr[0][w]); mx1 = fmaxf(mx1, rr[1][w]); }
      float p0 = __expf(e0 - mx0), p1 = __expf(e1 - mx1);
      float s0 = p0, s1 = p1;
#pragma unroll
      for (int off = 1; off < 64; off <<= 1) { s0 += __shfl_xor(s0, off); s1 += __shfl_xor(s1, off); }
      if (lane == 0) { rr[0][8 + wv] = s0; rr[1][8 + wv] = s1; }
      __syncthreads();
      float S0 = 0.f, S1 = 0.f;
#pragma unroll
      for (int w = 0; w < 8; ++w) { S0 += rr[0][8 + w]; S1 += rr[1][8 + w]; }
      ea[0][t] = p0 / S0; ea[1][t] = p1 / S1;
    }
    __syncthreads();
    // ---- context[b] = sum_t alpha_t * pre_out[b][t]   (waves 0-3 -> b0, 4-7 -> b1; global stream)
    {
      int bb = wv >> 2, wu = wv & 3;
      int d8 = lane & 15, g4 = lane >> 4, tg = wu * 4 + g4;
      const uint4* pb = (const uint4*)(pre16 + (size_t)(b0 + bb) * (TX_ * NS_));
      float p8[8];
#pragma unroll
      for (int j = 0; j < 8; ++j) p8[j] = 0.f;
      for (int i = 0; i < 32; ++i) {
        int t = i * 16 + tg;
        float al = ea[bb][t];
        uint4 pk = pb[t * 16 + d8];
        p8[0] += al * bflo(pk.x); p8[1] += al * bfhi(pk.x);
        p8[2] += al * bflo(pk.y); p8[3] += al * bfhi(pk.y);
        p8[4] += al * bflo(pk.z); p8[5] += al * bfhi(pk.z);
        p8[6] += al * bflo(pk.w); p8[7] += al * bfhi(pk.w);
      }
#pragma unroll
      for (int off = 16; off < 64; off <<= 1) {
#pragma unroll
        for (int j = 0; j < 8; ++j) p8[j] += __shfl_xor(p8[j], off);
      }
      if (lane < 16) {
        float4* dst = (float4*)&red[(bb * 4 + wu) * 128 + d8 * 8];
        dst[0] = make_float4(p8[0], p8[1], p8[2], p8[3]);
        dst[1] = make_float4(p8[4], p8[5], p8[6], p8[7]);
      }
    }
    __syncthreads();
    if (tid < 128) {   // fold 4-wave partials, pack ctx -> f16 pairs
      int bb = tid >> 6, jj = tid & 63;
      float v0 = 0.f, v1 = 0.f;
#pragma unroll
      for (int w = 0; w < 4; ++w) { v0 += red[(bb * 4 + w) * 128 + 2 * jj]; v1 += red[(bb * 4 + w) * 128 + 2 * jj + 1]; }
      xpk[bb][jj] = packf16(v0, v1);
    }
    __syncthreads();
    // ---- z[b][j] = Wcat[j] @ [ctx;s][b] + bp   (thread = j, f16 dot2, both batches per weight load)
    {
      float za0 = 0.f, zb0 = 0.f, za1 = 0.f, zb1 = 0.f;
      const uint4* wr = (const uint4*)(const void*)Wsw;
#pragma unroll 8
      for (int it = 0; it < 32; ++it) {
        uint4 w4 = wr[it * 512 + tid];
        uint4 x0 = *(const uint4*)&xpk[0][it * 4];
        uint4 x1 = *(const uint4*)&xpk[1][it * 4];
        za0 = dot2(w4.x, x0.x, za0); zb0 = dot2(w4.y, x0.y, zb0);
        za0 = dot2(w4.z, x0.z, za0); zb0 = dot2(w4.w, x0.w, zb0);
        za1 = dot2(w4.x, x1.x, za1); zb1 = dot2(w4.y, x1.y, zb1);
        za1 = dot2(w4.z, x1.z, za1); zb1 = dot2(w4.w, x1.w, zb1);
      }
      zbuf[0][tid] = za0 + zb0 + bpj;
      zbuf[1][tid] = za1 + zb1 + bpj;
    }
    __syncthreads();
    if (tid < 256) {   // gate merge i,f,g,o ; c,s update
      int bb = tid >> 7, idx = tid & 127;
      float zi = zbuf[bb][idx], zf = zbuf[bb][128 + idx], zg = zbuf[bb][256 + idx], zo = zbuf[bb][384 + idx];
      creg = sigm(zf) * creg + sigm(zi) * tanh_f(zg);
      sl[bb][idx] = sigm(zo) * tanh_f(creg);
    }
    __syncthreads();
    if (tid < 128) {   // pack s -> f16 pairs for next z
      int bb = tid >> 6, jj = tid & 63;
      xpk[bb][64 + jj] = packf16(sl[bb][2 * jj], sl[bb][2 * jj + 1]);
    }
    {   // logits partials: thread = (b, v, kgroup)
      int bb = tid >> 8, r = tid & 255, v = r >> 3, kg = r & 7;
      float a = 0.f;
#pragma unroll
      for (int k = kg * 16; k < kg * 16 + 16; ++k) a += sl[bb][k] * W3[v * 128 + k];
      red[bb * 256 + v * 8 + kg] = a;
    }
    __syncthreads();
    if (tid < 64) {
      int bb = tid >> 5, v = tid & 31;
      float a = b3[v];
#pragma unroll
      for (int i = 0; i < 8; ++i) a += red[bb * 256 + v * 8 + i];
      Lg[(size_t)ty * (B_ * VOUT_) + (size_t)(b0 + bb) * VOUT_ + v] = a;
    }
    __syncthreads();
  }
}

// ---------------- batch-softmax: per (ty,v) max & sum over b
__global__ __launch_bounds__(256) void k_red(const float* __restrict__ Lg, float2* __restrict__ MS) {
  int ty = blockIdx.x >> 5, v = blockIdx.x & 31;
  const float* src = Lg + (size_t)ty * (B_ * VOUT_) + v;
  int tid = threadIdx.x, lane = tid & 63, wv = tid >> 6;
  __shared__ float r8[8];
  float m = -3.4e38f;
  for (int bb = tid; bb < B_; bb += 256) m = fmaxf(m, src[(size_t)bb * VOUT_]);
#pragma unroll
  for (int off = 1; off < 64; off <<= 1) m = fmaxf(m, __shfl_xor(m, off));
  if (lane == 0) r8[wv] = m;
  __syncthreads();
  float mx = fmaxf(fmaxf(r8[0], r8[1]), fmaxf(r8[2], r8[3]));
  float s = 0.f;
  for (int bb = tid; bb < B_; bb += 256) s += __expf(src[(size_t)bb * VOUT_] - mx);
#pragma unroll
  for (int off = 1; off < 64; off <<= 1) s += __shfl_xor(s, off);
  __syncthreads();
  if (lane == 0) r8[4 + wv] = s;
  __syncthreads();
  if (tid == 0) MS[blockIdx.x] = make_float2(mx, r8[4] + r8[5] + r8[6] + r8[7]);
}

__global__ __launch_bounds__(256) void k_out(const float* __restrict__ Lg,
                                             const float2* __restrict__ MS,
                                             float* __restrict__ out) {
  int i = blockIdx.x * 256 + threadIdx.x;          // < 1048576, layout (ty,b,v)
  int ty = i >> 15, b = (i >> 5) & 1023, v = i & 31;
  float2 ms = MS[ty * 32 + v];
  out[(size_t)b * (TY_ * VOUT_) + ty * VOUT_ + v] = __expf(Lg[i] - ms.x) / ms.y;
}

// ---------------- ws layout (bytes): pre16 134217728 | Wsw 262144 | Lg 4194304 | MS 8192
#define WS_PRE 0
#define WS_WSW 134217728
#define WS_LG  134479872
#define WS_MS  138674176

extern "C" void kernel_launch(void* const* d_in, const int* in_sizes, int n_in,
                              void* d_out, int out_size, void* d_ws, size_t ws_size,
                              hipStream_t stream) {
  const float* X     = (const float*)d_in[0];
  const float* Wih_f = (const float*)d_in[1];
  const float* Whh_f = (const float*)d_in[2];
  const float* bih_f = (const float*)d_in[3];
  const float* bhh_f = (const float*)d_in[4];
  const float* Wih_b = (const float*)d_in[5];
  const float* Whh_b = (const float*)d_in[6];
  const float* bih_b = (const float*)d_in[7];
  const float* bhh_b = (const float*)d_in[8];
  const float* Wih_p = (const float*)d_in[9];
  const float* Whh_p = (const float*)d_in[10];
  const float* bih_p = (const float*)d_in[11];
  const float* bhh_p = (const float*)d_in[12];
  const float* W1    = (const float*)d_in[13];
  const float* b1    = (const float*)d_in[14];
  const float* W2    = (const float*)d_in[15];
  const float* b2    = (const float*)d_in[16];
  const float* W3    = (const float*)d_in[17];
  const float* b3    = (const float*)d_in[18];

  char* ws = (char*)d_ws;
  unsigned short* pre16 = (unsigned short*)(ws + WS_PRE);
  unsigned short* Wsw   = (unsigned short*)(ws + WS_WSW);
  float*          Lg    = (float*)(ws + WS_LG);
  float2*         MS    = (float2*)(ws + WS_MS);

  k_prep<<<512, 256, 0, stream>>>(Wih_p, Whh_p, Wsw);
  k_enc<<<128, 256, 0, stream>>>(X, Wih_f, Whh_f, bih_f, bhh_f,
                                 Wih_b, Whh_b, bih_b, bhh_b, pre16);
  k_dec<<<512, 512, 0, stream>>>(pre16, Wsw, W1, b1, W2, b2, W3, b3,
                                 bih_p, bhh_p, Lg);
  k_red<<<1024, 256, 0, stream>>>(Lg, MS);
  k_out<<<4096, 256, 0, stream>>>(Lg, MS, (float*)d_out);
}

// Round 4
// 2076.066 us; speedup vs baseline: 1.4404x; 1.4404x over previous
//
#include <hip/hip_runtime.h>
#include <stdint.h>

#define B_    1024
#define TX_   512
#define TY_   32
#define NA_   64
#define NS_   128
#define VIN_  64
#define VOUT_ 32

typedef short v8s __attribute__((ext_vector_type(8)));   // 8 bf16 (4 VGPRs)
typedef float v4f __attribute__((ext_vector_type(4)));   // 4 fp32 acc
typedef _Float16 h2 __attribute__((ext_vector_type(2))); // packed f16 pair

__device__ __forceinline__ unsigned short f2bf(float f) {
  union { float f; uint32_t u; } v; v.f = f;
  return (unsigned short)((v.u + 0x7fffu + ((v.u >> 16) & 1u)) >> 16);  // RNE
}
__device__ __forceinline__ float bflo(uint32_t p) { union { uint32_t u; float f; } v; v.u = p << 16; return v.f; }
__device__ __forceinline__ float bfhi(uint32_t p) { union { uint32_t u; float f; } v; v.u = p & 0xffff0000u; return v.f; }
__device__ __forceinline__ float sigm(float x)   { return 1.0f / (1.0f + __expf(-x)); }
__device__ __forceinline__ float tanh_f(float x) { return 1.0f - 2.0f / (__expf(2.0f * x) + 1.0f); }

__device__ __forceinline__ uint32_t packf16(float a, float b) {
  union { h2 h; uint32_t u; } v; v.h[0] = (_Float16)a; v.h[1] = (_Float16)b; return v.u;
}
__device__ __forceinline__ float dot2(uint32_t w, uint32_t x, float acc) {
  union { uint32_t u; h2 h; } a, b; a.u = w; b.u = x;
#if __has_builtin(__builtin_amdgcn_fdot2)
  return __builtin_amdgcn_fdot2(a.h, b.h, acc, false);
#else
  return acc + (float)a.h[0] * (float)b.h[0] + (float)a.h[1] * (float)b.h[1];
#endif
}

// ---------------- prep: Wcat = [Wih_p | Whh_p] -> f16, swizzled [k/8][j][8] for coalesced streaming
__global__ __launch_bounds__(256) void k_prep(const float* __restrict__ Wih_p,
                                              const float* __restrict__ Whh_p,
                                              unsigned short* __restrict__ Wsw) {
  int i = blockIdx.x * 256 + threadIdx.x;   // < 512*256
  int j = i >> 8, k = i & 255;
  float w = (k < 128) ? Wih_p[j * 128 + k] : Whh_p[j * 128 + (k - 128)];
  union { _Float16 h; unsigned short s; } cv; cv.h = (_Float16)w;
  Wsw[(((k >> 3) * 512 + j) << 3) + (k & 7)] = cv.s;
}

// ---------------- encoder: unchanged (MFMA 16x16x32, weights in VGPR B-frags)
__global__ __launch_bounds__(256) void k_enc(
    const float* __restrict__ X,
    const float* __restrict__ Wih_f, const float* __restrict__ Whh_f,
    const float* __restrict__ bih_f, const float* __restrict__ bhh_f,
    const float* __restrict__ Wih_b, const float* __restrict__ Whh_b,
    const float* __restrict__ bih_b, const float* __restrict__ bhh_b,
    unsigned short* __restrict__ pre16)
{
  const int tid = threadIdx.x, lane = tid & 63, wv = tid >> 6;
  const int dir = blockIdx.x & 1, b0 = (blockIdx.x >> 1) * 16;
  const int n = lane & 15, q = lane >> 4, hs = wv * 16;
  const float* Wih = dir ? Wih_b : Wih_f;
  const float* Whh = dir ? Whh_b : Whh_f;
  const float* bih = dir ? bih_b : bih_f;
  const float* bhh = dir ? bhh_b : bhh_f;

  __shared__ __align__(16) unsigned short hl[16 * 72];  // h bf16 [m][k], 144B row stride

  v8s wx[4][2], wh[4][2];
  float bias[4];
#pragma unroll
  for (int g = 0; g < 4; ++g) {
    int row = g * 64 + hs + n;
    bias[g] = bih[row] + bhh[row];
#pragma unroll
    for (int kt = 0; kt < 2; ++kt) {
      const float* pi = Wih + row * 64 + kt * 32 + q * 8;
      const float* ph = Whh + row * 64 + kt * 32 + q * 8;
      v8s a, bb;
#pragma unroll
      for (int j = 0; j < 8; ++j) { a[j] = (short)f2bf(pi[j]); bb[j] = (short)f2bf(ph[j]); }
      wx[g][kt] = a; wh[g][kt] = bb;
    }
  }
  for (int i = tid; i < 16 * 36; i += 256) ((uint32_t*)hl)[i] = 0u;

  float c[4] = {0.f, 0.f, 0.f, 0.f};
  const float* xrow = X + (size_t)(b0 + n) * (TX_ * VIN_) + q * 8;
  int t0 = dir ? (TX_ - 1) : 0;
  float4 pf0 = *(const float4*)(xrow + t0 * VIN_ + 0);
  float4 pf1 = *(const float4*)(xrow + t0 * VIN_ + 4);
  float4 pf2 = *(const float4*)(xrow + t0 * VIN_ + 32);
  float4 pf3 = *(const float4*)(xrow + t0 * VIN_ + 36);
  __syncthreads();

  for (int t = 0; t < TX_; ++t) {
    v8s xa0, xa1;
    xa0[0]=(short)f2bf(pf0.x); xa0[1]=(short)f2bf(pf0.y); xa0[2]=(short)f2bf(pf0.z); xa0[3]=(short)f2bf(pf0.w);
    xa0[4]=(short)f2bf(pf1.x); xa0[5]=(short)f2bf(pf1.y); xa0[6]=(short)f2bf(pf1.z); xa0[7]=(short)f2bf(pf1.w);
    xa1[0]=(short)f2bf(pf2.x); xa1[1]=(short)f2bf(pf2.y); xa1[2]=(short)f2bf(pf2.z); xa1[3]=(short)f2bf(pf2.w);
    xa1[4]=(short)f2bf(pf3.x); xa1[5]=(short)f2bf(pf3.y); xa1[6]=(short)f2bf(pf3.z); xa1[7]=(short)f2bf(pf3.w);
    int tn = (t + 1 < TX_) ? t + 1 : t;
    int ti = dir ? (TX_ - 1 - tn) : tn;
    pf0 = *(const float4*)(xrow + ti * VIN_ + 0);
    pf1 = *(const float4*)(xrow + ti * VIN_ + 4);
    pf2 = *(const float4*)(xrow + ti * VIN_ + 32);
    pf3 = *(const float4*)(xrow + ti * VIN_ + 36);

    v8s ha0 = *(const v8s*)((const char*)hl + (lane & 15) * 144 + q * 16);
    v8s ha1 = *(const v8s*)((const char*)hl + (lane & 15) * 144 + 64 + q * 16);
    v4f acc[4];
#pragma unroll
    for (int g = 0; g < 4; ++g) {
      v4f a = {bias[g], bias[g], bias[g], bias[g]};
      a = __builtin_amdgcn_mfma_f32_16x16x32_bf16(xa0, wx[g][0], a, 0, 0, 0);
      a = __builtin_amdgcn_mfma_f32_16x16x32_bf16(xa1, wx[g][1], a, 0, 0, 0);
      a = __builtin_amdgcn_mfma_f32_16x16x32_bf16(ha0, wh[g][0], a, 0, 0, 0);
      a = __builtin_amdgcn_mfma_f32_16x16x32_bf16(ha1, wh[g][1], a, 0, 0, 0);
      acc[g] = a;
    }
    __syncthreads();
    int t_out = dir ? (TX_ - 1 - t) : t;
#pragma unroll
    for (int r = 0; r < 4; ++r) {
      float cc = sigm(acc[1][r]) * c[r] + sigm(acc[0][r]) * tanh_f(acc[2][r]);
      c[r] = cc;
      float h = sigm(acc[3][r]) * tanh_f(cc);
      int m = q * 4 + r;
      unsigned short hb = f2bf(h);
      *((unsigned short*)((char*)hl + m * 144) + hs + n) = hb;
      pre16[((size_t)(b0 + m) * TX_ + t_out) * NS_ + dir * 64 + hs + n] = hb;
    }
    __syncthreads();
  }
}

// ---------------- decoder v3.1: 1024 blocks x 1024 thr, pre_out LDS-resident, P in regs, f16 dot2 z
// LDS layout (bytes)
#define PO_   0        // 512 x 272  = 139264  (pre_out bf16, padded rows)
#define EA_   139264   // 512 f32    = 2048    (alphas)
#define RED_  141312   // 2048 f32   = 8192    (ctx partials / z / logits partials; w1p overlay in prologue)
#define SL_   149504   // 128 f32    (s state)
#define XPK_  150016   // 128 u32    (f16x2 packed [ctx | s])
#define QV_   150528   // 16 f32
#define RR_   150592   // 16 f32
#define DSM_  150656

__global__ __launch_bounds__(1024, 4) void k_dec(
    const unsigned short* __restrict__ pre16,
    const unsigned short* __restrict__ Wsw,   // f16 [k/8][j][8]
    const float* __restrict__ W1, const float* __restrict__ b1,
    const float* __restrict__ W2, const float* __restrict__ b2,
    const float* __restrict__ W3, const float* __restrict__ b3,
    const float* __restrict__ bih_p, const float* __restrict__ bhh_p,
    float* __restrict__ Lg)
{
  extern __shared__ char smem[];
  char*     po  = smem + PO_;
  float*    ea  = (float*)(smem + EA_);
  float*    red = (float*)(smem + RED_);
  float*    sl  = (float*)(smem + SL_);
  uint32_t* xpk = (uint32_t*)(smem + XPK_);
  float*    qv  = (float*)(smem + QV_);
  float*    rr  = (float*)(smem + RR_);
  float*    w1p = (float*)(smem + RED_);    // prologue-only overlay (5120 B <= 8192)

  const int tid = threadIdx.x, lane = tid & 63, wv = tid >> 6;
  const int b = blockIdx.x;

  { // stage pre_out[b] -> LDS (272B rows)
    const uint4* src = (const uint4*)(pre16 + (size_t)b * (TX_ * NS_));
    for (int i = tid; i < TX_ * 16; i += 1024) {
      int t = i >> 4, d8 = i & 15;
      *(uint4*)(po + t * 272 + d8 * 16) = src[i];
    }
  }
  if (tid < 128) { sl[tid] = 0.f; xpk[tid] = 0u; }
  if (tid < 16)  qv[tid] = 0.f;
  for (int i = tid; i < 1280; i += 1024) w1p[i] = W1[(i >> 7) * 256 + 128 + (i & 127)];
  float bpi = 0.f, bpf = 0.f, bpg = 0.f, bpo = 0.f, creg = 0.f;
  if (tid < 128) {
    bpi = bih_p[tid]       + bhh_p[tid];
    bpf = bih_p[128 + tid] + bhh_p[128 + tid];
    bpg = bih_p[256 + tid] + bhh_p[256 + tid];
    bpo = bih_p[384 + tid] + bhh_p[384 + tid];
  }
  __syncthreads();

  // P[t][0..9] = pre_out[t] @ W1[:,128:].T + b1  -> registers of threads 0..511 (bf16-packed)
  uint32_t Pr[5] = {0u, 0u, 0u, 0u, 0u};
  if (tid < 512) {
    float a[10];
#pragma unroll
    for (int g = 0; g < 10; ++g) a[g] = b1[g];
    const uint4* prow = (const uint4*)(po + tid * 272);
    for (int i = 0; i < 32; ++i) {
      uint4 pk = prow[i];
      float v0 = bflo(pk.x), v1 = bfhi(pk.x), v2 = bflo(pk.y), v3 = bfhi(pk.y);
      float v4 = bflo(pk.z), v5 = bfhi(pk.z), v6 = bflo(pk.w), v7 = bfhi(pk.w);
#pragma unroll
      for (int g = 0; g < 10; ++g) {
        const float* wg = w1p + g * 128 + i * 8;
        a[g] += v0*wg[0] + v1*wg[1] + v2*wg[2] + v3*wg[3] + v4*wg[4] + v5*wg[5] + v6*wg[6] + v7*wg[7];
      }
    }
#pragma unroll
    for (int j = 0; j < 5; ++j)
      Pr[j] = ((uint32_t)f2bf(a[2 * j + 1]) << 16) | (uint32_t)f2bf(a[2 * j]);
  }

  for (int ty = 0; ty < TY_; ++ty) {
    // ---- Phase E: finalize prev logits (tid<32) + e_t (tid<512) + softmax max
    float e_val = 0.f, pexp = 0.f;
    if (tid < 32 && ty > 0) {
      float a = b3[tid];
#pragma unroll
      for (int i = 0; i < 8; ++i) a += red[512 + tid * 8 + i];
      Lg[(size_t)(ty - 1) * (B_ * VOUT_) + (size_t)b * VOUT_ + tid] = a;
    }
    if (tid < 512) {
      float acc = b2[0];
#pragma unroll
      for (int i = 0; i < 5; ++i) {
        uint32_t pr = Pr[i];
        acc += W2[2 * i]     * tanh_f(bflo(pr) + qv[2 * i]);
        acc += W2[2 * i + 1] * tanh_f(bfhi(pr) + qv[2 * i + 1]);
      }
      e_val = fmaxf(acc, 0.f);
      float m = e_val;
#pragma unroll
      for (int off = 1; off < 64; off <<= 1) m = fmaxf(m, __shfl_xor(m, off));
      if (lane == 0) rr[wv] = m;
    }
    __syncthreads();                                   // (1)
    if (tid < 512) {
      float mx = rr[0];
#pragma unroll
      for (int w = 1; w < 8; ++w) mx = fmaxf(mx, rr[w]);
      pexp = __expf(e_val - mx);
      float s = pexp;
#pragma unroll
      for (int off = 1; off < 64; off <<= 1) s += __shfl_xor(s, off);
      if (lane == 0) rr[8 + wv] = s;
    }
    __syncthreads();                                   // (2)
    if (tid < 512) {
      float S = 0.f;
#pragma unroll
      for (int w = 0; w < 8; ++w) S += rr[8 + w];
      ea[tid] = pexp / S;
    }
    __syncthreads();                                   // (3)
    // ---- Phase C: context partials (all 16 waves)
    {
      int d8 = lane & 15, g4 = lane >> 4;
      const char* pbase = po + d8 * 16;
      float p8[8];
#pragma unroll
      for (int j = 0; j < 8; ++j) p8[j] = 0.f;
#pragma unroll
      for (int i = 0; i < 8; ++i) {
        int t = i * 64 + wv * 4 + g4;
        float al = ea[t];
        uint4 pk = *(const uint4*)(pbase + t * 272);
        p8[0] += al * bflo(pk.x); p8[1] += al * bfhi(pk.x);
        p8[2] += al * bflo(pk.y); p8[3] += al * bfhi(pk.y);
        p8[4] += al * bflo(pk.z); p8[5] += al * bfhi(pk.z);
        p8[6] += al * bflo(pk.w); p8[7] += al * bfhi(pk.w);
      }
#pragma unroll
      for (int off = 16; off < 64; off <<= 1) {
#pragma unroll
        for (int j = 0; j < 8; ++j) p8[j] += __shfl_xor(p8[j], off);
      }
      if (lane < 16) {
        float4* dst = (float4*)&red[wv * 128 + d8 * 8];
        dst[0] = make_float4(p8[0], p8[1], p8[2], p8[3]);
        dst[1] = make_float4(p8[4], p8[5], p8[6], p8[7]);
      }
    }
    __syncthreads();                                   // (4)
    if (tid < 64) {  // fold 16 partials (2 floats each -> one f16x2 entry); ctx = xpk[0..63] ONLY
      float v0 = 0.f, v1 = 0.f;
#pragma unroll
      for (int w = 0; w < 16; ++w) {
        float2 rv = *(const float2*)&red[w * 128 + 2 * tid];
        v0 += rv.x; v1 += rv.y;
      }
      xpk[tid] = packf16(v0, v1);
    }
    __syncthreads();                                   // (5)
    // ---- Phase Z: z = Wcat @ [ctx;s]  (2 threads per row, f16 dot2)
    {
      int j = tid >> 1, h = tid & 1;
      const uint4* wr = (const uint4*)(const void*)Wsw + (size_t)h * 16 * 512 + j;
      const uint4* xq = (const uint4*)(const void*)xpk + h * 16;
      float za = 0.f, zb = 0.f;
#pragma unroll 8
      for (int it = 0; it < 16; ++it) {
        uint4 w4 = wr[(size_t)it * 512];
        uint4 x4 = xq[it];
        za = dot2(w4.x, x4.x, za); zb = dot2(w4.y, x4.y, zb);
        za = dot2(w4.z, x4.z, za); zb = dot2(w4.w, x4.w, zb);
      }
      float z = za + zb;
      z += __shfl_xor(z, 1);
      if (h == 0) red[j] = z;
    }
    __syncthreads();                                   // (6)
    if (tid < 128) {  // gates i,f,g,o
      float zi = red[tid] + bpi, zf = red[128 + tid] + bpf;
      float zg = red[256 + tid] + bpg, zo = red[384 + tid] + bpo;
      creg = sigm(zf) * creg + sigm(zi) * tanh_f(zg);
      sl[tid] = sigm(zo) * tanh_f(creg);
    }
    __syncthreads();                                   // (7)
    // ---- Phase G: pack-s (wave1) + q-next (wave0) + logits partials (waves 4-7)
    if (wv == 1) {
      xpk[64 + lane] = packf16(sl[2 * lane], sl[2 * lane + 1]);
    } else if (wv == 0) {
      float s0 = sl[lane], s1 = sl[64 + lane];
      float p10[10];
#pragma unroll
      for (int g = 0; g < 10; ++g) p10[g] = s0 * W1[g * 256 + lane] + s1 * W1[g * 256 + 64 + lane];
#pragma unroll
      for (int off = 1; off < 64; off <<= 1) {
#pragma unroll
        for (int g = 0; g < 10; ++g) p10[g] += __shfl_xor(p10[g], off);
      }
      if (lane < 10) qv[lane] = p10[lane];
    } else if (wv >= 4 && wv < 8) {
      int r = tid - 256, v = r >> 3, kg = r & 7;
      float a = 0.f;
#pragma unroll
      for (int k = kg * 16; k < kg * 16 + 16; ++k) a += sl[k] * W3[v * 128 + k];
      red[512 + v * 8 + kg] = a;
    }
    __syncthreads();                                   // (8)
  }
  if (tid < 32) {  // final step logits
    float a = b3[tid];
#pragma unroll
    for (int i = 0; i < 8; ++i) a += red[512 + tid * 8 + i];
    Lg[(size_t)(TY_ - 1) * (B_ * VOUT_) + (size_t)b * VOUT_ + tid] = a;
  }
}

// ---------------- batch-softmax: per (ty,v) max & sum over b
__global__ __launch_bounds__(256) void k_red(const float* __restrict__ Lg, float2* __restrict__ MS) {
  int ty = blockIdx.x >> 5, v = blockIdx.x & 31;
  const float* src = Lg + (size_t)ty * (B_ * VOUT_) + v;
  int tid = threadIdx.x, lane = tid & 63, wv = tid >> 6;
  __shared__ float r8[8];
  float m = -3.4e38f;
  for (int bb = tid; bb < B_; bb += 256) m = fmaxf(m, src[(size_t)bb * VOUT_]);
#pragma unroll
  for (int off = 1; off < 64; off <<= 1) m = fmaxf(m, __shfl_xor(m, off));
  if (lane == 0) r8[wv] = m;
  __syncthreads();
  float mx = fmaxf(fmaxf(r8[0], r8[1]), fmaxf(r8[2], r8[3]));
  float s = 0.f;
  for (int bb = tid; bb < B_; bb += 256) s += __expf(src[(size_t)bb * VOUT_] - mx);
#pragma unroll
  for (int off = 1; off < 64; off <<= 1) s += __shfl_xor(s, off);
  __syncthreads();
  if (lane == 0) r8[4 + wv] = s;
  __syncthreads();
  if (tid == 0) MS[blockIdx.x] = make_float2(mx, r8[4] + r8[5] + r8[6] + r8[7]);
}

__global__ __launch_bounds__(256) void k_out(const float* __restrict__ Lg,
                                             const float2* __restrict__ MS,
                                             float* __restrict__ out) {
  int i = blockIdx.x * 256 + threadIdx.x;          // < 1048576, layout (ty,b,v)
  int ty = i >> 15, b = (i >> 5) & 1023, v = i & 31;
  float2 ms = MS[ty * 32 + v];
  out[(size_t)b * (TY_ * VOUT_) + ty * VOUT_ + v] = __expf(Lg[i] - ms.x) / ms.y;
}

// ---------------- ws layout (bytes): pre16 134217728 | Wsw 262144 | Lg 4194304 | MS 8192
#define WS_PRE 0
#define WS_WSW 134217728
#define WS_LG  134479872
#define WS_MS  138674176

extern "C" void kernel_launch(void* const* d_in, const int* in_sizes, int n_in,
                              void* d_out, int out_size, void* d_ws, size_t ws_size,
                              hipStream_t stream) {
  const float* X     = (const float*)d_in[0];
  const float* Wih_f = (const float*)d_in[1];
  const float* Whh_f = (const float*)d_in[2];
  const float* bih_f = (const float*)d_in[3];
  const float* bhh_f = (const float*)d_in[4];
  const float* Wih_b = (const float*)d_in[5];
  const float* Whh_b = (const float*)d_in[6];
  const float* bih_b = (const float*)d_in[7];
  const float* bhh_b = (const float*)d_in[8];
  const float* Wih_p = (const float*)d_in[9];
  const float* Whh_p = (const float*)d_in[10];
  const float* bih_p = (const float*)d_in[11];
  const float* bhh_p = (const float*)d_in[12];
  const float* W1    = (const float*)d_in[13];
  const float* b1    = (const float*)d_in[14];
  const float* W2    = (const float*)d_in[15];
  const float* b2    = (const float*)d_in[16];
  const float* W3    = (const float*)d_in[17];
  const float* b3    = (const float*)d_in[18];

  char* ws = (char*)d_ws;
  unsigned short* pre16 = (unsigned short*)(ws + WS_PRE);
  unsigned short* Wsw   = (unsigned short*)(ws + WS_WSW);
  float*          Lg    = (float*)(ws + WS_LG);
  float2*         MS    = (float2*)(ws + WS_MS);

  (void)hipFuncSetAttribute((const void*)k_dec, hipFuncAttributeMaxDynamicSharedMemorySize, DSM_);

  k_prep<<<512, 256, 0, stream>>>(Wih_p, Whh_p, Wsw);
  k_enc<<<128, 256, 0, stream>>>(X, Wih_f, Whh_f, bih_f, bhh_f,
                                 Wih_b, Whh_b, bih_b, bhh_b, pre16);
  k_dec<<<1024, 1024, DSM_, stream>>>(pre16, Wsw, W1, b1, W2, b2, W3, b3,
                                      bih_p, bhh_p, Lg);
  k_red<<<1024, 256, 0, stream>>>(Lg, MS);
  k_out<<<4096, 256, 0, stream>>>(Lg, MS, (float*)d_out);
}